// Round 6
// baseline (166.028 us; speedup 1.0000x reference)
//
#include <hip/hip_runtime.h>
#include <hip/hip_bf16.h>
#include <hip/hip_cooperative_groups.h>

namespace cg = cooperative_groups;

#define IN 8192
#define OUT 8192

typedef __bf16 bf16x8 __attribute__((ext_vector_type(8)));
typedef float f32x4 __attribute__((ext_vector_type(4)));
typedef unsigned short u16;
typedef unsigned int u32;
typedef u32 u32x4 __attribute__((ext_vector_type(4)));

#define MFMA(a, b, c) __builtin_amdgcn_mfma_f32_16x16x32_bf16(a, b, c, 0, 0, 0)

static __device__ __forceinline__ u16 f2bf(float v) {
    __hip_bfloat16 h = __float2bfloat16(v);
    return __builtin_bit_cast(u16, h);
}
static __device__ __forceinline__ float bf2f(u16 h) {
    union { u32 u; float f; } cv; cv.u = ((u32)h) << 16; return cv.f;
}
static __device__ __forceinline__ bf16x8 ld8(const u16* p) {
    return *reinterpret_cast<const bf16x8*>(p);
}

// Single cooperative kernel, 5 phases separated by grid.sync():
//  P1: invv/invu build + tws = v1 @ X chunks        (128 active blocks: (b,nc))
//  P2: Z chunk = tws @ v2c^T -> scatter bf16 xt + Spart   (128 blocks: (b,lc))
//  P3: qgemm (round-3 v1 math, 8 waves/block)       (all 256 blocks)
//  P4: og gather + t2ws = u1^T @ og chunks          (128 blocks: (b,nc))
//  P5: Zp chunk = t2ws @ u2c -> scatter out + bias  (128 blocks: (b,lc))
__global__ __launch_bounds__(512)
void fused_kernel(const float* __restrict__ x, const int* __restrict__ qw,
                  const float* __restrict__ scale, const float* __restrict__ shw,
                  const float* __restrict__ v1, const float* __restrict__ v2,
                  const float* __restrict__ u1, const float* __restrict__ u2,
                  const float* __restrict__ bias,
                  const int* __restrict__ vinp, const int* __restrict__ voutp,
                  const int* __restrict__ uinp, const int* __restrict__ uoutp,
                  float* __restrict__ out,
                  u16* __restrict__ xt, float* __restrict__ tws,
                  float* __restrict__ G, float* __restrict__ t2ws,
                  float* __restrict__ Spart, int* __restrict__ invv,
                  int* __restrict__ invu) {
    __shared__ __align__(16) char smem[66048];
    cg::grid_group grid = cg::this_grid();
    const int tid = threadIdx.x, bid = blockIdx.x;
    const int lane = tid & 63, w = tid >> 6;
    const int l15 = lane & 15, l4 = lane >> 4;

    // ---------------- P1 ----------------
    {
        int g = bid * 512 + tid;
        if (g < 8192) { invv[voutp[g]] = g; invu[uinp[g]] = g; }
    }
    if (bid < 128) {
        const int b = bid >> 3, nc = bid & 7;
        float* v1s = (float*)smem;               // [64][65]
        float* Xs  = (float*)(smem + 16640);     // [16][65]  n-major
        #pragma unroll
        for (int it = 0; it < 8; ++it) {
            int e = tid + it * 512;              // e = i*64 + j
            v1s[(e >> 6) * 65 + (e & 63)] = v1[e];
        }
        #pragma unroll
        for (int it = 0; it < 2; ++it) {
            int e = tid + it * 512;              // e = j*16 + n
            int j = e >> 4, n = e & 15;
            int gi = vinp[j * 128 + nc * 16 + n];
            Xs[n * 65 + j] = x[b * IN + gi] / shw[gi];
        }
        __syncthreads();
        int i = tid & 63;
        int n0 = w, n1 = w + 8;
        float a0 = 0.f, a1 = 0.f;
        #pragma unroll
        for (int j = 0; j < 64; ++j) {
            float vv = v1s[i * 65 + j];
            a0 += vv * Xs[n0 * 65 + j];
            a1 += vv * Xs[n1 * 65 + j];
        }
        tws[((size_t)b * 64 + i) * 128 + nc * 16 + n0] = a0;
        tws[((size_t)b * 64 + i) * 128 + nc * 16 + n1] = a1;
    }
    grid.sync();

    // ---------------- P2 ----------------
    if (bid < 128) {
        const int b = bid >> 3, lc = bid & 7;
        float* Ts   = (float*)smem;              // [64][129]
        float* v2c  = (float*)(smem + 33024);    // [16][129]
        float* sred = (float*)(smem + 41280);    // [8]
        #pragma unroll
        for (int it = 0; it < 16; ++it) {
            int e = tid + it * 512;              // e = i*128 + k
            Ts[(e >> 7) * 129 + (e & 127)] = tws[(size_t)b * 8192 + e];
        }
        #pragma unroll
        for (int it = 0; it < 4; ++it) {
            int e = tid + it * 512;              // e = r*128 + k
            v2c[(e >> 7) * 129 + (e & 127)] = v2[(lc * 16 + (e >> 7)) * 128 + (e & 127)];
        }
        __syncthreads();
        int i = tid & 63;
        int l0 = w, l1 = w + 8;
        float a0 = 0.f, a1 = 0.f;
        #pragma unroll
        for (int k = 0; k < 128; ++k) {
            float tv = Ts[i * 129 + k];
            a0 += tv * v2c[l0 * 129 + k];
            a1 += tv * v2c[l1 * 129 + k];
        }
        u16 z0 = f2bf(a0), z1 = f2bf(a1);
        xt[(size_t)b * IN + invv[i * 128 + lc * 16 + l0]] = z0;
        xt[(size_t)b * IN + invv[i * 128 + lc * 16 + l1]] = z1;
        float ssum = bf2f(z0) + bf2f(z1);
        #pragma unroll
        for (int off = 32; off; off >>= 1) ssum += __shfl_down(ssum, off, 64);
        if (lane == 0) sred[w] = ssum;
        __syncthreads();
        if (tid == 0) {
            float s = 0.f;
            #pragma unroll
            for (int c = 0; c < 8; ++c) s += sred[c];
            Spart[b * 8 + lc] = s;
        }
    }
    grid.sync();

    // ---------------- P3: qgemm ----------------
    {
        u16* sA = (u16*)smem;                    // [16][2056]
        const int bx = bid & 63, by = bid >> 6;
        const int o0 = bx * 128, k0 = by * 2048;
        #pragma unroll
        for (int it = 0; it < 8; ++it) {
            int idx = it * 512 + tid;            // 0..4095
            int r = idx >> 8, c = idx & 255;
            *reinterpret_cast<u32x4*>(&sA[r * 2056 + c * 8]) =
                *reinterpret_cast<const u32x4*>(&xt[(size_t)r * IN + k0 + c * 8]);
        }
        __syncthreads();
        const int o = o0 + w * 16 + l15;
        const int* qp = qw + (size_t)(k0 / 8 + l4) * OUT + o;
        f32x4 acc = {0.f, 0.f, 0.f, 0.f};
        #pragma unroll 8
        for (int kt = 0; kt < 64; ++kt) {
            u32 q = (u32)qp[(size_t)kt * 4 * OUT];
            bf16x8 a = ld8(&sA[l15 * 2056 + kt * 32 + l4 * 8]);
            u32 ev = q & 0x0F0F0F0Fu, od = (q >> 4) & 0x0F0F0F0Fu;
            float f0, f1, f2, f3, f4, f5, f6, f7;
            asm("v_cvt_f32_ubyte0 %0, %1" : "=v"(f0) : "v"(ev));
            asm("v_cvt_f32_ubyte0 %0, %1" : "=v"(f1) : "v"(od));
            asm("v_cvt_f32_ubyte1 %0, %1" : "=v"(f2) : "v"(ev));
            asm("v_cvt_f32_ubyte1 %0, %1" : "=v"(f3) : "v"(od));
            asm("v_cvt_f32_ubyte2 %0, %1" : "=v"(f4) : "v"(ev));
            asm("v_cvt_f32_ubyte2 %0, %1" : "=v"(f5) : "v"(od));
            asm("v_cvt_f32_ubyte3 %0, %1" : "=v"(f6) : "v"(ev));
            asm("v_cvt_f32_ubyte3 %0, %1" : "=v"(f7) : "v"(od));
            u32 p0, p1, p2, p3;
            asm("v_cvt_pk_bf16_f32 %0, %1, %2" : "=v"(p0) : "v"(f0), "v"(f1));
            asm("v_cvt_pk_bf16_f32 %0, %1, %2" : "=v"(p1) : "v"(f2), "v"(f3));
            asm("v_cvt_pk_bf16_f32 %0, %1, %2" : "=v"(p2) : "v"(f4), "v"(f5));
            asm("v_cvt_pk_bf16_f32 %0, %1, %2" : "=v"(p3) : "v"(f6), "v"(f7));
            u32x4 pk = {p0, p1, p2, p3};
            acc = MFMA(a, __builtin_bit_cast(bf16x8, pk), acc);
        }
        float* g = G + ((size_t)by * 16 + l4 * 4) * OUT + o;
        #pragma unroll
        for (int r = 0; r < 4; ++r) g[(size_t)r * OUT] = acc[r];
    }
    grid.sync();

    // ---------------- P4 ----------------
    if (bid < 128) {
        const int b = bid >> 3, nc = bid & 7;
        float* u1s = (float*)smem;               // [64][65]  (u1^T: [i][j])
        float* ogs = (float*)(smem + 16640);     // [64][17]  j-major
        float Sb = 0.f;
        #pragma unroll
        for (int c = 0; c < 8; ++c) Sb += Spart[b * 8 + c];
        #pragma unroll
        for (int it = 0; it < 8; ++it) {
            int e = tid + it * 512;              // e = j*64 + i
            u1s[(e & 63) * 65 + (e >> 6)] = u1[e];
        }
        #pragma unroll
        for (int it = 0; it < 2; ++it) {
            int e = tid + it * 512;              // e = j*16 + n
            int j = e >> 4, n = e & 15;
            int o = uoutp[j * 128 + nc * 16 + n];
            float gs = G[(size_t)b * OUT + o] + G[(size_t)(16 + b) * OUT + o]
                     + G[(size_t)(32 + b) * OUT + o] + G[(size_t)(48 + b) * OUT + o];
            ogs[j * 17 + n] = scale[o] * (gs * (2.0f / 15.0f) - Sb);
        }
        __syncthreads();
        int i = tid & 63;
        int n0 = w, n1 = w + 8;
        float a0 = 0.f, a1 = 0.f;
        #pragma unroll
        for (int j = 0; j < 64; ++j) {
            float uv = u1s[i * 65 + j];
            a0 += uv * ogs[j * 17 + n0];
            a1 += uv * ogs[j * 17 + n1];
        }
        t2ws[((size_t)b * 64 + i) * 128 + nc * 16 + n0] = a0;
        t2ws[((size_t)b * 64 + i) * 128 + nc * 16 + n1] = a1;
    }
    grid.sync();

    // ---------------- P5 ----------------
    if (bid < 128) {
        const int b = bid >> 3, lc = bid & 7;
        float* t2s = (float*)smem;               // [64][129]
        float* u2c = (float*)(smem + 33024);     // [16][129]
        #pragma unroll
        for (int it = 0; it < 16; ++it) {
            int e = tid + it * 512;              // e = i*128 + k
            t2s[(e >> 7) * 129 + (e & 127)] = t2ws[(size_t)b * 8192 + e];
        }
        #pragma unroll
        for (int it = 0; it < 4; ++it) {
            int e = tid + it * 512;              // e = k*16 + l
            int l = e & 15, k = e >> 4;
            u2c[l * 129 + k] = u2[k * 128 + lc * 16 + l];
        }
        __syncthreads();
        int i = tid & 63;
        int l0 = w, l1 = w + 8;
        float a0 = 0.f, a1 = 0.f;
        #pragma unroll
        for (int k = 0; k < 128; ++k) {
            float tv = t2s[i * 129 + k];
            a0 += tv * u2c[l0 * 129 + k];
            a1 += tv * u2c[l1 * 129 + k];
        }
        int p0 = invu[i * 128 + lc * 16 + l0];
        int p1 = invu[i * 128 + lc * 16 + l1];
        out[(size_t)b * OUT + p0] = a0 + bias[p0];
        out[(size_t)b * OUT + p1] = a1 + bias[p1];
    }
}

extern "C" void kernel_launch(void* const* d_in, const int* in_sizes, int n_in,
                              void* d_out, int out_size, void* d_ws, size_t ws_size,
                              hipStream_t stream) {
    const float* x     = (const float*)d_in[0];
    const int*   qw    = (const int*)d_in[1];
    const float* scale = (const float*)d_in[2];
    const float* shw   = (const float*)d_in[3];
    const float* v1    = (const float*)d_in[4];
    const float* v2    = (const float*)d_in[5];
    const float* u1    = (const float*)d_in[6];
    const float* u2    = (const float*)d_in[7];
    const float* bias  = (const float*)d_in[8];
    const int* vinp  = (const int*)d_in[9];
    const int* voutp = (const int*)d_in[10];
    const int* uinp  = (const int*)d_in[11];
    const int* uoutp = (const int*)d_in[12];
    float* out = (float*)d_out;

    char* ws = (char*)d_ws;
    u16*   xt    = (u16*)ws;                     // 256 KiB  [16][8192] bf16
    float* G     = (float*)(ws + (256 << 10));   // 2 MiB    [4][16][8192] f32
    float* tws   = (float*)(ws + (2304 << 10));  // 512 KiB  [16][64][128] f32
    float* t2ws  = (float*)(ws + (2816 << 10));  // 512 KiB  [16][64][128] f32
    float* Spart = (float*)(ws + (3328 << 10));  // 512 B    [16][8] f32
    int*   invv  = (int*)(ws + (3329 << 10));    // 32 KiB
    int*   invu  = (int*)(ws + (3361 << 10));    // 32 KiB

    void* args[] = {
        (void*)&x, (void*)&qw, (void*)&scale, (void*)&shw,
        (void*)&v1, (void*)&v2, (void*)&u1, (void*)&u2, (void*)&bias,
        (void*)&vinp, (void*)&voutp, (void*)&uinp, (void*)&uoutp,
        (void*)&out, (void*)&xt, (void*)&tws, (void*)&G, (void*)&t2ws,
        (void*)&Spart, (void*)&invv, (void*)&invu
    };
    hipLaunchCooperativeKernel(reinterpret_cast<void*>(fused_kernel),
                               dim3(256), dim3(512), args, 0, stream);
}

// Round 7
// 108.508 us; speedup vs baseline: 1.5301x; 1.5301x over previous
//
#include <hip/hip_runtime.h>
#include <hip/hip_bf16.h>

#define IN 8192
#define OUT 8192

typedef __bf16 bf16x8 __attribute__((ext_vector_type(8)));
typedef float f32x4 __attribute__((ext_vector_type(4)));
typedef unsigned short u16;
typedef unsigned int u32;
typedef u32 u32x4 __attribute__((ext_vector_type(4)));

#define MFMA(a, b, c) __builtin_amdgcn_mfma_f32_16x16x32_bf16(a, b, c, 0, 0, 0)

static __device__ __forceinline__ u16 f2bf(float v) {
    __hip_bfloat16 h = __float2bfloat16(v);
    return __builtin_bit_cast(u16, h);
}
static __device__ __forceinline__ float bf2f(u16 h) {
    union { u32 u; float f; } cv; cv.u = ((u32)h) << 16; return cv.f;
}
static __device__ __forceinline__ void split_hl(float v, u16& hi, u16& lo) {
    hi = f2bf(v);
    lo = f2bf(v - bf2f(hi));
}
static __device__ __forceinline__ bf16x8 ld8(const u16* p) {
    return *reinterpret_cast<const bf16x8*>(p);
}

// ================= pre: butterfly-in + scatter to bf16 xt + S[b]  (R3 form, validated) =================
__global__ __launch_bounds__(1024)
void pre_kernel(const float* __restrict__ x, const float* __restrict__ shw,
                const int* __restrict__ vinp, const int* __restrict__ voutp,
                const float* __restrict__ v1, const float* __restrict__ v2,
                u16* __restrict__ xt, float* __restrict__ S, int* __restrict__ cnt) {
    __shared__ alignas(16) u16 sV1[2][64 * 72];     // v1 hi/lo, [i][j] stride 72
    __shared__ alignas(16) u16 sXb[2][128 * 72];    // X^T [n][j] stride 72; reused as T [i][k] stride 136
    __shared__ alignas(16) u16 sV2[2][128 * 136];   // v2 [l][k] stride 136
    __shared__ float sred[16];
    const int tid = threadIdx.x, b = blockIdx.x;
    const int lane = tid & 63, w = tid >> 6;
    const int l15 = lane & 15, l4 = lane >> 4;
    if (b == 0 && tid == 0) *cnt = 0;               // reset K2's completion counter

    #pragma unroll
    for (int it = 0; it < 4; ++it) {                // v1: 4096
        int e = tid + it * 1024;
        u16 h, l; split_hl(v1[e], h, l);
        int idx = (e >> 6) * 72 + (e & 63);
        sV1[0][idx] = h; sV1[1][idx] = l;
    }
    #pragma unroll
    for (int it = 0; it < 16; ++it) {               // v2: 16384, natural [l][k]
        int e = tid + it * 1024;
        u16 h, l; split_hl(v2[e], h, l);
        int idx = (e >> 7) * 136 + (e & 127);
        sV2[0][idx] = h; sV2[1][idx] = l;
    }
    int qidx[8];
    #pragma unroll
    for (int it = 0; it < 8; ++it) qidx[it] = vinp[tid + it * 1024];
    #pragma unroll
    for (int it = 0; it < 8; ++it) {                // X gather, store transposed [n][j]
        int q = qidx[it];
        float v = x[b * IN + q] / shw[q];
        u16 h, l; split_hl(v, h, l);
        int e = tid + it * 1024;
        int idx = (e & 127) * 72 + (e >> 7);
        sXb[0][idx] = h; sXb[1][idx] = l;
    }
    __syncthreads();

    // stage1: T = v1 @ X  (M=64,N=128,K=64). wave: n-tile nt, m-half mh.
    const int nt = w & 7, mh = w >> 3;
    f32x4 acc0 = {0.f, 0.f, 0.f, 0.f}, acc1 = {0.f, 0.f, 0.f, 0.f};
    #pragma unroll
    for (int ks = 0; ks < 2; ++ks) {
        int boff = (nt * 16 + l15) * 72 + ks * 32 + l4 * 8;
        bf16x8 bh = ld8(&sXb[0][boff]), bl = ld8(&sXb[1][boff]);
        int a0 = (mh * 32 + l15) * 72 + ks * 32 + l4 * 8;
        int a1 = a0 + 16 * 72;
        bf16x8 ah0 = ld8(&sV1[0][a0]), al0 = ld8(&sV1[1][a0]);
        bf16x8 ah1 = ld8(&sV1[0][a1]), al1 = ld8(&sV1[1][a1]);
        acc0 = MFMA(ah0, bh, acc0); acc0 = MFMA(ah0, bl, acc0); acc0 = MFMA(al0, bh, acc0);
        acc1 = MFMA(ah1, bh, acc1); acc1 = MFMA(ah1, bl, acc1); acc1 = MFMA(al1, bh, acc1);
    }
    __syncthreads();                                // all waves done reading sXb
    u16* Thi = sXb[0]; u16* Tlo = sXb[1];           // T [i][k] stride 136
    #pragma unroll
    for (int m = 0; m < 2; ++m) {
        f32x4 a = m ? acc1 : acc0;
        #pragma unroll
        for (int r = 0; r < 4; ++r) {
            int i = mh * 32 + m * 16 + l4 * 4 + r;
            u16 h, l; split_hl(a[r], h, l);
            Thi[i * 136 + nt * 16 + l15] = h;
            Tlo[i * 136 + nt * 16 + l15] = l;
        }
    }
    __syncthreads();

    // stage2: Z = T @ v2^T  (M=64,N=128,K=128)
    f32x4 z0 = {0.f, 0.f, 0.f, 0.f}, z1 = {0.f, 0.f, 0.f, 0.f};
    #pragma unroll
    for (int ks = 0; ks < 4; ++ks) {
        int boff = (nt * 16 + l15) * 136 + ks * 32 + l4 * 8;
        bf16x8 bh = ld8(&sV2[0][boff]), bl = ld8(&sV2[1][boff]);
        int a0 = (mh * 32 + l15) * 136 + ks * 32 + l4 * 8;
        int a1 = a0 + 16 * 136;
        bf16x8 ah0 = ld8(&Thi[a0]), al0 = ld8(&Tlo[a0]);
        bf16x8 ah1 = ld8(&Thi[a1]), al1 = ld8(&Tlo[a1]);
        z0 = MFMA(ah0, bh, z0); z0 = MFMA(ah0, bl, z0); z0 = MFMA(al0, bh, z0);
        z1 = MFMA(ah1, bh, z1); z1 = MFMA(ah1, bl, z1); z1 = MFMA(al1, bh, z1);
    }
    __syncthreads();
    u16* Zl = &sV1[0][0];                           // 8192 u16, reuse v1 region
    #pragma unroll
    for (int m = 0; m < 2; ++m) {
        f32x4 zz = m ? z1 : z0;
        #pragma unroll
        for (int r = 0; r < 4; ++r) {
            int i = mh * 32 + m * 16 + l4 * 4 + r;
            Zl[i * 128 + nt * 16 + l15] = f2bf(zz[r]);
        }
    }
    __syncthreads();
    float ssum = 0.f;
    #pragma unroll
    for (int it = 0; it < 8; ++it) {
        int p = tid + it * 1024;
        u16 zb = Zl[voutp[p]];
        xt[(size_t)b * IN + p] = zb;
        ssum += bf2f(zb);
    }
    #pragma unroll
    for (int off = 32; off; off >>= 1) ssum += __shfl_down(ssum, off, 64);
    if (lane == 0) sred[w] = ssum;
    __syncthreads();
    if (tid == 0) {
        float t = 0.f;
        #pragma unroll
        for (int i = 0; i < 16; ++i) t += sred[i];
        S[b] = t;
    }
}

// ================= K2: qgemm (256 blocks x 512 thr) + last-16-finisher post epilogue =================
__global__ __launch_bounds__(512)
void gemm_post_kernel(const int* __restrict__ qw, const u16* __restrict__ xt,
                      const float* __restrict__ S, const float* __restrict__ scale,
                      const float* __restrict__ u1, const float* __restrict__ u2,
                      const float* __restrict__ bias,
                      const int* __restrict__ uinp, const int* __restrict__ uoutp,
                      float* __restrict__ G, float* __restrict__ out,
                      int* __restrict__ cnt) {
    __shared__ alignas(16) char smem[124928];
    __shared__ int sOld;
    const int tid = threadIdx.x, bid = blockIdx.x;
    const int lane = tid & 63, w = tid >> 6;
    const int l15 = lane & 15, l4 = lane >> 4;

    // ---------------- qgemm phase (R6-P3 validated form) ----------------
    {
        u16* sA = (u16*)smem;                       // [16][2056] u16 = 64.25 KiB
        const int bx = bid & 63, by = bid >> 6;
        const int o0 = bx * 128, k0 = by * 2048;
        #pragma unroll
        for (int it = 0; it < 8; ++it) {
            int idx = it * 512 + tid;               // 0..4095
            int r = idx >> 8, c = idx & 255;
            *reinterpret_cast<u32x4*>(&sA[r * 2056 + c * 8]) =
                *reinterpret_cast<const u32x4*>(&xt[(size_t)r * IN + k0 + c * 8]);
        }
        __syncthreads();
        const int o = o0 + w * 16 + l15;
        const int* qp = qw + (size_t)(k0 / 8 + l4) * OUT + o;
        f32x4 acc = {0.f, 0.f, 0.f, 0.f};
        #pragma unroll 8
        for (int kt = 0; kt < 64; ++kt) {
            u32 q = (u32)qp[(size_t)kt * 4 * OUT];
            bf16x8 a = ld8(&sA[l15 * 2056 + kt * 32 + l4 * 8]);
            u32 ev = q & 0x0F0F0F0Fu, od = (q >> 4) & 0x0F0F0F0Fu;
            float f0, f1, f2, f3, f4, f5, f6, f7;
            asm("v_cvt_f32_ubyte0 %0, %1" : "=v"(f0) : "v"(ev));
            asm("v_cvt_f32_ubyte0 %0, %1" : "=v"(f1) : "v"(od));
            asm("v_cvt_f32_ubyte1 %0, %1" : "=v"(f2) : "v"(ev));
            asm("v_cvt_f32_ubyte1 %0, %1" : "=v"(f3) : "v"(od));
            asm("v_cvt_f32_ubyte2 %0, %1" : "=v"(f4) : "v"(ev));
            asm("v_cvt_f32_ubyte2 %0, %1" : "=v"(f5) : "v"(od));
            asm("v_cvt_f32_ubyte3 %0, %1" : "=v"(f6) : "v"(ev));
            asm("v_cvt_f32_ubyte3 %0, %1" : "=v"(f7) : "v"(od));
            u32 p0, p1, p2, p3;
            asm("v_cvt_pk_bf16_f32 %0, %1, %2" : "=v"(p0) : "v"(f0), "v"(f1));
            asm("v_cvt_pk_bf16_f32 %0, %1, %2" : "=v"(p1) : "v"(f2), "v"(f3));
            asm("v_cvt_pk_bf16_f32 %0, %1, %2" : "=v"(p2) : "v"(f4), "v"(f5));
            asm("v_cvt_pk_bf16_f32 %0, %1, %2" : "=v"(p3) : "v"(f6), "v"(f7));
            u32x4 pk = {p0, p1, p2, p3};
            acc = MFMA(a, __builtin_bit_cast(bf16x8, pk), acc);
        }
        float* g = G + ((size_t)by * 16 + l4 * 4) * OUT + o;
        #pragma unroll
        for (int r = 0; r < 4; ++r) g[(size_t)r * OUT] = acc[r];
    }

    // ---------------- completion counter; last 16 finishers run post ----------------
    __threadfence();                                // make G writes device-visible
    if (tid == 0) sOld = atomicAdd(cnt, 1);
    __syncthreads();
    const int old = sOld;
    if (old < 240) return;
    if (tid == 0) {
        while (atomicAdd(cnt, 0) < 256) __builtin_amdgcn_s_sleep(2);
    }
    __syncthreads();
    __threadfence();                                // acquire: see all G writes
    const int b = old - 240;

    // ---------------- post phase (R3 post body, 512 threads) ----------------
    u16* sU1h = (u16*)smem;                         // [64][72]
    u16* sU1l = sU1h + 64 * 72;
    u16* sOGh = sU1l + 64 * 72;                     // [128][72]; reused as T [i][k] stride 136
    u16* sOGl = sOGh + 128 * 72;
    u16* sU2h = sOGl + 128 * 72;                    // [128][136]; reused as Zp f32[8192]
    u16* sU2l = sU2h + 128 * 136;
    const float Sb = S[b];

    #pragma unroll
    for (int it = 0; it < 8; ++it) {                // u1^T: u1[j*64+i] -> [i][j]
        int e = tid + it * 512;
        u16 h, l; split_hl(u1[e], h, l);
        int idx = (e & 63) * 72 + (e >> 6);
        sU1h[idx] = h; sU1l[idx] = l;
    }
    #pragma unroll
    for (int it = 0; it < 32; ++it) {               // u2^T: u2[k*128+l] -> [l][k]
        int e = tid + it * 512;
        u16 h, l; split_hl(u2[e], h, l);
        int idx = (e & 127) * 136 + (e >> 7);
        sU2h[idx] = h; sU2l[idx] = l;
    }
    #pragma unroll
    for (int it = 0; it < 16; ++it) {               // og gather -> og^T [n][j]
        int e = tid + it * 512;
        int o = uoutp[e];
        float gs = G[(size_t)b * OUT + o] + G[(size_t)(16 + b) * OUT + o]
                 + G[(size_t)(32 + b) * OUT + o] + G[(size_t)(48 + b) * OUT + o];
        float v = scale[o] * (gs * (2.0f / 15.0f) - Sb);
        u16 h, l; split_hl(v, h, l);
        int idx = (e & 127) * 72 + (e >> 7);
        sOGh[idx] = h; sOGl[idx] = l;
    }
    __syncthreads();

    // stage1: t2 = u1^T @ og  (M=64,N=128,K=64). wave w = n-tile, acc[4] m-tiles.
    f32x4 acc[4] = {{0,0,0,0},{0,0,0,0},{0,0,0,0},{0,0,0,0}};
    #pragma unroll
    for (int ks = 0; ks < 2; ++ks) {
        int boff = (w * 16 + l15) * 72 + ks * 32 + l4 * 8;
        bf16x8 bh = ld8(&sOGh[boff]), bl = ld8(&sOGl[boff]);
        #pragma unroll
        for (int mt = 0; mt < 4; ++mt) {
            int ao = (mt * 16 + l15) * 72 + ks * 32 + l4 * 8;
            bf16x8 ah = ld8(&sU1h[ao]), al = ld8(&sU1l[ao]);
            acc[mt] = MFMA(ah, bh, acc[mt]);
            acc[mt] = MFMA(ah, bl, acc[mt]);
            acc[mt] = MFMA(al, bh, acc[mt]);
        }
    }
    __syncthreads();
    u16* Thi = sOGh; u16* Tlo = sOGl;               // T [i][k] stride 136
    #pragma unroll
    for (int mt = 0; mt < 4; ++mt) {
        #pragma unroll
        for (int r = 0; r < 4; ++r) {
            int i = mt * 16 + l4 * 4 + r;
            u16 h, l; split_hl(acc[mt][r], h, l);
            Thi[i * 136 + w * 16 + l15] = h;
            Tlo[i * 136 + w * 16 + l15] = l;
        }
    }
    __syncthreads();

    // stage2: Zp = t2 @ u2  (M=64,N=128,K=128). wave w = n-tile, z[4] m-tiles.
    f32x4 z[4] = {{0,0,0,0},{0,0,0,0},{0,0,0,0},{0,0,0,0}};
    #pragma unroll
    for (int ks = 0; ks < 4; ++ks) {
        int boff = (w * 16 + l15) * 136 + ks * 32 + l4 * 8;
        bf16x8 bh = ld8(&sU2h[boff]), bl = ld8(&sU2l[boff]);
        #pragma unroll
        for (int mt = 0; mt < 4; ++mt) {
            int ao = (mt * 16 + l15) * 136 + ks * 32 + l4 * 8;
            bf16x8 ah = ld8(&Thi[ao]), al = ld8(&Tlo[ao]);
            z[mt] = MFMA(ah, bh, z[mt]);
            z[mt] = MFMA(ah, bl, z[mt]);
            z[mt] = MFMA(al, bh, z[mt]);
        }
    }
    __syncthreads();                                // done reading sU2
    float* Zp = reinterpret_cast<float*>(sU2h);
    #pragma unroll
    for (int mt = 0; mt < 4; ++mt) {
        #pragma unroll
        for (int r = 0; r < 4; ++r) {
            int i = mt * 16 + l4 * 4 + r;
            Zp[i * 128 + w * 16 + l15] = z[mt][r];
        }
    }
    __syncthreads();
    #pragma unroll
    for (int it = 0; it < 16; ++it) {
        int p = tid + it * 512;
        out[(size_t)b * OUT + p] = Zp[uinp[p]] + bias[p];
    }
}

extern "C" void kernel_launch(void* const* d_in, const int* in_sizes, int n_in,
                              void* d_out, int out_size, void* d_ws, size_t ws_size,
                              hipStream_t stream) {
    const float* x     = (const float*)d_in[0];
    const int*   qw    = (const int*)d_in[1];
    const float* scale = (const float*)d_in[2];
    const float* shw   = (const float*)d_in[3];
    const float* v1    = (const float*)d_in[4];
    const float* v2    = (const float*)d_in[5];
    const float* u1    = (const float*)d_in[6];
    const float* u2    = (const float*)d_in[7];
    const float* bias  = (const float*)d_in[8];
    const int* vinp  = (const int*)d_in[9];
    const int* voutp = (const int*)d_in[10];
    const int* uinp  = (const int*)d_in[11];
    const int* uoutp = (const int*)d_in[12];
    float* out = (float*)d_out;

    char* ws = (char*)d_ws;
    u16*   xt  = (u16*)ws;                          // 256 KiB  [16][8192] bf16
    float* G   = (float*)(ws + (256 << 10));        // 2 MiB    [4][16][8192] f32
    float* S   = (float*)(ws + (2304 << 10));       // 64 B     [16] f32
    int*   cnt = (int*)(ws + (2308 << 10));         // 4 B

    pre_kernel<<<16, 1024, 0, stream>>>(x, shw, vinp, voutp, v1, v2, xt, S, cnt);
    gemm_post_kernel<<<256, 512, 0, stream>>>(qw, xt, S, scale, u1, u2, bias,
                                              uinp, uoutp, G, out, cnt);
}